// Round 5
// baseline (252.674 us; speedup 1.0000x reference)
//
#include <hip/hip_runtime.h>
#include <hip/hip_bf16.h>

#define CIN   256
#define COUT  32
#define IMG_H 96
#define IMG_W 96
#define HW    (IMG_H*IMG_W)
#define NB    2
#define NV    4
#define VSZ   64
#define NVOX  (VSZ*VSZ*VSZ)
#define CH_TILE 64

typedef __attribute__((ext_vector_type(2))) float f32x2;

__device__ __forceinline__ float fast_exp2(float x) {
    float r;
    asm("v_exp_f32 %0, %1" : "=v"(r) : "v"(x));
    return r;
}

// async global->LDS DMA, 4 B per lane. LDS dest must be wave-uniform;
// HW writes dest + lane*4. Global src is per-lane.
__device__ __forceinline__ void gload_lds4(const float* g, float* l) {
    __builtin_amdgcn_global_load_lds(
        (const __attribute__((address_space(1))) void*)g,
        (__attribute__((address_space(3))) void*)l,
        4, 0, 0);
}

// Kernel 1 (R9): 1x1 conv -> channel-last bf16 [b,v,h,w,c].
// R7/R8 post-mortem: VGPR double-buffering the per-lane strided stream is
// a dead end (44.7 -> 100/109 us; VGPR 88 halved wave pool, bursts bought
// nothing). R9 = the guide's canonical fix: global_load_lds staging.
// Block (4 waves) owns one 64-px strip; each channel strip is DMA'd into
// LDS ONCE per block (4x fewer global requests than R6's per-wave reads);
// waves compute their 8 couts from LDS (2-way bank access = free).
// T3-minimal schedule: STAGE(next) -> COMPUTE(cur) -> __syncthreads();
// barrier's implicit vmcnt(0) drain covered by compute > load latency.
__global__ __launch_bounds__(256) void conv1x1_kernel(
    const float* __restrict__ features,   // [B,V,CIN,H,W] fp32
    const float* __restrict__ Wp,         // [COUT,CIN]
    const float* __restrict__ bp,         // [COUT]
    __hip_bfloat16* __restrict__ out)     // [B,V,H,W,COUT] bf16
{
    __shared__ float sbuf[2][CH_TILE*64];          // 32 KB, double-buffered
    const int og   = __builtin_amdgcn_readfirstlane((threadIdx.x >> 6) & 3);
    const int lane = threadIdx.x & 63;
    const int bv   = blockIdx.y;
    const int px0  = blockIdx.x*64;
    const float* fpx   = features + (size_t)bv*CIN*HW + px0 + lane; // per-lane
    const float* wbase = Wp + (size_t)og*8*CIN;    // uniform -> scalar path

    float acc[8];
    #pragma unroll
    for (int j = 0; j < 8; ++j) acc[j] = bp[og*8 + j];   // uniform -> s_load

    // prologue: stage tile 0 (wave og stages channels og*16 .. og*16+15)
    #pragma unroll
    for (int i = 0; i < 16; ++i)
        gload_lds4(fpx + (size_t)(og*16 + i)*HW, &sbuf[0][(og*16 + i)*64]);
    __syncthreads();                                // drains vmcnt(0)

    #pragma unroll
    for (int t = 0; t < CIN/CH_TILE; ++t) {         // 4 tiles of 64 ch
        const int cur = t & 1;
        if (t + 1 < CIN/CH_TILE) {                  // stage next tile
            #pragma unroll
            for (int i = 0; i < 16; ++i)
                gload_lds4(fpx + (size_t)((t+1)*CH_TILE + og*16 + i)*HW,
                           &sbuf[cur ^ 1][(og*16 + i)*64]);
        }
        #pragma unroll
        for (int c = 0; c < CH_TILE; ++c) {         // compute current tile
            const float x = sbuf[cur][c*64 + lane]; // bank = lane%32: free
            #pragma unroll
            for (int j = 0; j < 8; ++j)             // v_fmac v, s, v
                acc[j] += x * wbase[(size_t)j*CIN + t*CH_TILE + c];
        }
        __syncthreads();   // all waves done reading cur; next-tile DMA done
    }

    union { uint4 u4; __hip_bfloat16 h[8]; } pk;
    #pragma unroll
    for (int j = 0; j < 8; ++j) pk.h[j] = __float2bfloat16(acc[j]);
    *(uint4*)(out + ((size_t)(bv*HW + px0 + lane))*COUT + og*8) = pk.u4;
}

// Kernel 2 (unchanged from R6; ~43us, re-attack after conv is fixed).
__global__ __launch_bounds__(256, 4) void volgen_kernel(
    const __hip_bfloat16* __restrict__ feats,  // [B,V,H,W,COUT] bf16
    const float* __restrict__ proj,            // [B,V,3,4]
    const float* __restrict__ coords,          // [B,NVOX,3]
    float* __restrict__ out)                   // [B,COUT,NVOX]
{
    const int tid = threadIdx.x;
    const int b   = blockIdx.y;
    const int n   = blockIdx.x*256 + tid;

    const float* cp = coords + ((size_t)b*NVOX + n)*3;
    const float X = cp[0], Y = cp[1], Z = cp[2];

    const float LOG2E = 1.4426950408889634f;

    int   off[NV][4];                          // byte offsets into feats
    float wgt[NV][4];                          // bilinear weight * log2(e)
    #pragma unroll
    for (int v = 0; v < NV; ++v) {
        const float* P = proj + (size_t)(b*NV + v)*12;   // uniform -> scalar
        const float wz = P[8]*X + P[9]*Y + P[10]*Z + P[11];
        const bool  vz = wz > 0.f;
        const float rz = __builtin_amdgcn_rcpf(wz);
        float px = (P[0]*X + P[1]*Y + P[2]*Z + P[3]) * rz * (95.f/96.f);
        float py = (P[4]*X + P[5]*Y + P[6]*Z + P[7]) * rz * (95.f/96.f);
        px = vz ? px : 0.f;  py = vz ? py : 0.f;
        px = fminf(fmaxf(px, -1.0e6f), 1.0e6f);
        py = fminf(fmaxf(py, -1.0e6f), 1.0e6f);
        const float fx0 = floorf(px), fy0 = floorf(py);
        const int x0 = (int)fx0, y0 = (int)fy0, x1 = x0+1, y1 = y0+1;
        const float wx1 = px - fx0, wx0 = 1.f - wx1;
        const float wy1 = py - fy0, wy0 = 1.f - wy1;
        const bool vx0 = (unsigned)x0 < (unsigned)IMG_W;
        const bool vx1 = (unsigned)x1 < (unsigned)IMG_W;
        const bool vy0 = (unsigned)y0 < (unsigned)IMG_H;
        const bool vy1 = (unsigned)y1 < (unsigned)IMG_H;
        const int cx0 = min(max(x0, 0), IMG_W-1), cx1 = min(max(x1, 0), IMG_W-1);
        const int cy0 = min(max(y0, 0), IMG_H-1), cy1 = min(max(y1, 0), IMG_H-1);
        const int base = ((b*NV + v)*HW)*COUT*2;         // bytes, uniform
        off[v][0] = base + (cy0*IMG_W + cx0)*(COUT*2);  wgt[v][0] = (vz & vx0 & vy0) ? wx0*wy0*LOG2E : 0.f;
        off[v][1] = base + (cy0*IMG_W + cx1)*(COUT*2);  wgt[v][1] = (vz & vx1 & vy0) ? wx1*wy0*LOG2E : 0.f;
        off[v][2] = base + (cy1*IMG_W + cx0)*(COUT*2);  wgt[v][2] = (vz & vx0 & vy1) ? wx0*wy1*LOG2E : 0.f;
        off[v][3] = base + (cy1*IMG_W + cx1)*(COUT*2);  wgt[v][3] = (vz & vx1 & vy1) ? wx1*wy1*LOG2E : 0.f;
    }

    const char* fb = (const char*)feats;
    const size_t ob = (size_t)b*COUT*NVOX + n;
    const float LN2 = 0.6931471805599453f;

    for (int ch0 = 0; ch0 < COUT; ch0 += 8) {
        f32x2 A2[4], B2[4];
        uint4 t[4], tn[4];

        #pragma unroll
        for (int c = 0; c < 4; ++c)                     // prime the pipeline
            t[c] = *(const uint4*)(fb + off[0][c] + ch0*2);

        #pragma unroll
        for (int v = 0; v < NV; ++v) {
            if (v < NV-1) {
                #pragma unroll
                for (int c = 0; c < 4; ++c)             // prefetch next view
                    tn[c] = *(const uint4*)(fb + off[v+1][c] + ch0*2);
            }

            f32x2 s2[4];
            #pragma unroll
            for (int c = 0; c < 4; ++c) {
                const float w = wgt[v][c];
                const f32x2 w2 = { w, w };
                const unsigned tu[4] = { t[c].x, t[c].y, t[c].z, t[c].w };
                #pragma unroll
                for (int k = 0; k < 4; ++k) {           // packed fma: 2 ch/instr
                    f32x2 f2;
                    f2.x = __uint_as_float(tu[k] << 16);
                    f2.y = __uint_as_float(tu[k] & 0xffff0000u);
                    if (c == 0) s2[k] = w2 * f2;        // no zero-init
                    else        s2[k] += w2 * f2;
                }
            }

            #pragma unroll
            for (int k = 0; k < 4; ++k) {
                f32x2 e2;
                e2.x = fast_exp2(s2[k].x);              // wgt pre-scaled: 2^s' = e^s
                e2.y = fast_exp2(s2[k].y);
                if (v == 0) { A2[k] = e2;  B2[k] = s2[k]*e2; }
                else        { A2[k] += e2; B2[k] += s2[k]*e2; }
            }

            if (v < NV-1) {
                #pragma unroll
                for (int c = 0; c < 4; ++c) t[c] = tn[c];   // rotate
            }
        }

        #pragma unroll
        for (int k = 0; k < 4; ++k) {                   // coalesced stores
            out[ob + (size_t)(ch0 + 2*k    )*NVOX] = B2[k].x * __builtin_amdgcn_rcpf(A2[k].x) * LN2;
            out[ob + (size_t)(ch0 + 2*k + 1)*NVOX] = B2[k].y * __builtin_amdgcn_rcpf(A2[k].y) * LN2;
        }
    }
}

extern "C" void kernel_launch(void* const* d_in, const int* in_sizes, int n_in,
                              void* d_out, int out_size, void* d_ws, size_t ws_size,
                              hipStream_t stream)
{
    const float* features = (const float*)d_in[0];   // [2,4,256,96,96]
    const float* proj     = (const float*)d_in[1];   // [2,4,3,4]
    const float* coords   = (const float*)d_in[2];   // [2,64,64,64,3]
    const float* Wp       = (const float*)d_in[3];   // [32,256]
    const float* bp       = (const float*)d_in[4];   // [32]
    float* out = (float*)d_out;                      // [2,32,64,64,64]
    __hip_bfloat16* featsT = (__hip_bfloat16*)d_ws;  // [2,4,96,96,32] bf16 = 4.72 MB

    hipLaunchKernelGGL(conv1x1_kernel, dim3(HW/64, NB*NV), dim3(256), 0, stream,
                       features, Wp, bp, featsT);
    hipLaunchKernelGGL(volgen_kernel, dim3(NVOX/256, NB), dim3(256), 0, stream,
                       featsT, proj, coords, out);
}

// Round 6
// 179.496 us; speedup vs baseline: 1.4077x; 1.4077x over previous
//
#include <hip/hip_runtime.h>
#include <hip/hip_bf16.h>

#define CIN   256
#define COUT  32
#define IMG_H 96
#define IMG_W 96
#define HW    (IMG_H*IMG_W)
#define NB    2
#define NV    4
#define VSZ   64
#define NVOX  (VSZ*VSZ*VSZ)

typedef __attribute__((ext_vector_type(2))) float f32x2;

__device__ __forceinline__ float fast_exp2(float x) {
    float r;
    asm("v_exp_f32 %0, %1" : "=v"(r) : "v"(x));
    return r;
}

// Kernel 1 (R10 = R6 verbatim): 1x1 conv -> channel-last bf16 [b,v,h,w,c].
// R7 (VGPR dbuf, split blocks): 100us. R8 (VGPR dbuf, shared strip): 109us.
// R9 (global_load_lds staging): 122us, VGPR 132. All three lost to this
// "naive" version (44.7us, VGPR 16): 18 waves/CU x ~2 outstanding 256B
// loads = 9.2KB in flight/CU = ~6.8 TB/s on the 302MB 4x-redundant demand.
// Raising per-wave MLP always cost more occupancy than it bought. KEEP.
__global__ __launch_bounds__(256) void conv1x1_kernel(
    const float* __restrict__ features,   // [B,V,CIN,H,W] fp32
    const float* __restrict__ Wp,         // [COUT,CIN]
    const float* __restrict__ bp,         // [COUT]
    __hip_bfloat16* __restrict__ out)     // [B,V,H,W,COUT] bf16
{
    const int og   = __builtin_amdgcn_readfirstlane((threadIdx.x >> 6) & 3);
    const int lane = threadIdx.x & 63;
    const int bv   = blockIdx.y;
    const int px   = blockIdx.x*64 + lane;
    const float* f     = features + (size_t)bv*CIN*HW + px;
    const float* wbase = Wp + (size_t)og*8*CIN;     // uniform -> scalar base

    float acc[8];
    #pragma unroll
    for (int j = 0; j < 8; ++j) acc[j] = bp[og*8 + j];   // uniform -> s_load

    for (int cc = 0; cc < CIN; cc += 8) {
        float x[8];
        #pragma unroll
        for (int i = 0; i < 8; ++i)                  // 8 indep coalesced loads
            x[i] = f[(size_t)(cc + i)*HW];
        #pragma unroll
        for (int i = 0; i < 8; ++i) {
            #pragma unroll
            for (int j = 0; j < 8; ++j)              // v_fmac v, s, v
                acc[j] += x[i] * wbase[(size_t)j*CIN + cc + i];
        }
    }

    union { uint4 u4; __hip_bfloat16 h[8]; } pk;
    #pragma unroll
    for (int j = 0; j < 8; ++j) pk.h[j] = __float2bfloat16(acc[j]);
    *(uint4*)(out + ((size_t)(bv*HW + px))*COUT + og*8) = pk.u4;
}

// Kernel 2 (R10): voxel-per-lane + WAVE-COHERENT FRUSTUM SKIP.
// Data insight: coords = randn*1000, proj = randn -> projected px,py are
// Cauchy-like with O(1) scale; only a small fraction of (voxel,view)
// pairs land inside the 96x96 image (+ wz>0). Out-of-frustum contribution
// is EXACTLY s=0 -> e=1 -> A+=1, B+=0. Adjacent lanes are adjacent voxels
// (z-fastest) -> skip predicate is wave-coherent -> per-view __ballot
// gives a wave-uniform SGPR branch: skip all 16 gathers + 64 pk-fma +
// 8 transcendentals for dead views; fold the skipped-view count into the
// accumulator init. Bit-exact vs the branchless path.
__global__ __launch_bounds__(256, 4) void volgen_kernel(
    const __hip_bfloat16* __restrict__ feats,  // [B,V,H,W,COUT] bf16
    const float* __restrict__ proj,            // [B,V,3,4]
    const float* __restrict__ coords,          // [B,NVOX,3]
    float* __restrict__ out)                   // [B,COUT,NVOX]
{
    const int tid = threadIdx.x;
    const int b   = blockIdx.y;
    const int n   = blockIdx.x*256 + tid;

    const float* cp = coords + ((size_t)b*NVOX + n)*3;
    const float X = cp[0], Y = cp[1], Z = cp[2];

    const float LOG2E = 1.4426950408889634f;

    int   off[NV][4];                          // byte offsets into feats
    float wgt[NV][4];                          // bilinear weight * log2(e)
    #pragma unroll
    for (int v = 0; v < NV; ++v) {
        const float* P = proj + (size_t)(b*NV + v)*12;   // uniform -> scalar
        const float wz = P[8]*X + P[9]*Y + P[10]*Z + P[11];
        const bool  vz = wz > 0.f;
        const float rz = __builtin_amdgcn_rcpf(wz);
        float px = (P[0]*X + P[1]*Y + P[2]*Z + P[3]) * rz * (95.f/96.f);
        float py = (P[4]*X + P[5]*Y + P[6]*Z + P[7]) * rz * (95.f/96.f);
        px = vz ? px : 0.f;  py = vz ? py : 0.f;
        px = fminf(fmaxf(px, -1.0e6f), 1.0e6f);
        py = fminf(fmaxf(py, -1.0e6f), 1.0e6f);
        const float fx0 = floorf(px), fy0 = floorf(py);
        const int x0 = (int)fx0, y0 = (int)fy0, x1 = x0+1, y1 = y0+1;
        const float wx1 = px - fx0, wx0 = 1.f - wx1;
        const float wy1 = py - fy0, wy0 = 1.f - wy1;
        const bool vx0 = (unsigned)x0 < (unsigned)IMG_W;
        const bool vx1 = (unsigned)x1 < (unsigned)IMG_W;
        const bool vy0 = (unsigned)y0 < (unsigned)IMG_H;
        const bool vy1 = (unsigned)y1 < (unsigned)IMG_H;
        const int cx0 = min(max(x0, 0), IMG_W-1), cx1 = min(max(x1, 0), IMG_W-1);
        const int cy0 = min(max(y0, 0), IMG_H-1), cy1 = min(max(y1, 0), IMG_H-1);
        const int base = ((b*NV + v)*HW)*COUT*2;         // bytes, uniform
        off[v][0] = base + (cy0*IMG_W + cx0)*(COUT*2);  wgt[v][0] = (vz & vx0 & vy0) ? wx0*wy0*LOG2E : 0.f;
        off[v][1] = base + (cy0*IMG_W + cx1)*(COUT*2);  wgt[v][1] = (vz & vx1 & vy0) ? wx1*wy0*LOG2E : 0.f;
        off[v][2] = base + (cy1*IMG_W + cx0)*(COUT*2);  wgt[v][2] = (vz & vx0 & vy1) ? wx0*wy1*LOG2E : 0.f;
        off[v][3] = base + (cy1*IMG_W + cx1)*(COUT*2);  wgt[v][3] = (vz & vx1 & vy1) ? wx1*wy1*LOG2E : 0.f;
    }

    // Wave-level view activity: vmask[v]==0 -> NO lane in this wave samples
    // view v -> skip it entirely; its exact contribution is A += 1.
    unsigned long long vmask[NV];
    #pragma unroll
    for (int v = 0; v < NV; ++v)
        vmask[v] = __ballot((wgt[v][0] + wgt[v][1] + wgt[v][2] + wgt[v][3]) > 0.f);
    float skipadd = 0.f;
    #pragma unroll
    for (int v = 0; v < NV; ++v)
        skipadd += (vmask[v] == 0ull) ? 1.f : 0.f;       // wave-uniform

    const char* fb = (const char*)feats;
    const size_t ob = (size_t)b*COUT*NVOX + n;
    const float LN2 = 0.6931471805599453f;

    for (int ch0 = 0; ch0 < COUT; ch0 += 8) {
        f32x2 A2[4], B2[4];
        #pragma unroll
        for (int k = 0; k < 4; ++k) {
            A2[k] = (f32x2){ skipadd, skipadd };         // skipped views: e=1
            B2[k] = (f32x2)(0.f);                        // skipped views: s*e=0
        }

        #pragma unroll
        for (int v = 0; v < NV; ++v) {
            if (vmask[v]) {                              // wave-uniform branch
                uint4 t[4];
                #pragma unroll
                for (int c = 0; c < 4; ++c)              // 4 gathers in flight
                    t[c] = *(const uint4*)(fb + off[v][c] + ch0*2);

                f32x2 s2[4];
                #pragma unroll
                for (int c = 0; c < 4; ++c) {
                    const float w = wgt[v][c];
                    const f32x2 w2 = { w, w };
                    const unsigned tu[4] = { t[c].x, t[c].y, t[c].z, t[c].w };
                    #pragma unroll
                    for (int k = 0; k < 4; ++k) {        // packed fma: 2 ch/instr
                        f32x2 f2;
                        f2.x = __uint_as_float(tu[k] << 16);
                        f2.y = __uint_as_float(tu[k] & 0xffff0000u);
                        if (c == 0) s2[k] = w2 * f2;     // no zero-init
                        else        s2[k] += w2 * f2;
                    }
                }

                #pragma unroll
                for (int k = 0; k < 4; ++k) {
                    f32x2 e2;
                    e2.x = fast_exp2(s2[k].x);           // wgt pre-scaled: 2^s' = e^s
                    e2.y = fast_exp2(s2[k].y);
                    A2[k] += e2;
                    B2[k] += s2[k]*e2;
                }
            }
        }

        #pragma unroll
        for (int k = 0; k < 4; ++k) {                    // coalesced stores
            out[ob + (size_t)(ch0 + 2*k    )*NVOX] = B2[k].x * __builtin_amdgcn_rcpf(A2[k].x) * LN2;
            out[ob + (size_t)(ch0 + 2*k + 1)*NVOX] = B2[k].y * __builtin_amdgcn_rcpf(A2[k].y) * LN2;
        }
    }
}

extern "C" void kernel_launch(void* const* d_in, const int* in_sizes, int n_in,
                              void* d_out, int out_size, void* d_ws, size_t ws_size,
                              hipStream_t stream)
{
    const float* features = (const float*)d_in[0];   // [2,4,256,96,96]
    const float* proj     = (const float*)d_in[1];   // [2,4,3,4]
    const float* coords   = (const float*)d_in[2];   // [2,64,64,64,3]
    const float* Wp       = (const float*)d_in[3];   // [32,256]
    const float* bp       = (const float*)d_in[4];   // [32]
    float* out = (float*)d_out;                      // [2,32,64,64,64]
    __hip_bfloat16* featsT = (__hip_bfloat16*)d_ws;  // [2,4,96,96,32] bf16 = 4.72 MB

    hipLaunchKernelGGL(conv1x1_kernel, dim3(HW/64, NB*NV), dim3(256), 0, stream,
                       features, Wp, bp, featsT);
    hipLaunchKernelGGL(volgen_kernel, dim3(NVOX/256, NB), dim3(256), 0, stream,
                       featsT, proj, coords, out);
}